// Round 1
// baseline (936.163 us; speedup 1.0000x reference)
//
#include <hip/hip_runtime.h>
#include <math.h>

#define VOC 50000
#define EMB 300
#define BSZ 256
#define CTX 6
#define KNEG 10
#define ROW_VECS (VOC / 4)   // 12500 float4 per one-hot row; VOC % 4 == 0 so vecs never straddle rows

// Scan a [rows x VOC] one-hot f32 array; write the nonzero column of each row
// into out_idx[row]. Rows that are all-zero (padded vi contexts) are left
// untouched (caller pre-memsets out_idx to -1).
__global__ void scan_onehot_kernel(const float4* __restrict__ data,
                                   int nvecs,
                                   int* __restrict__ out_idx) {
    int stride = gridDim.x * blockDim.x;
    for (int j = blockIdx.x * blockDim.x + threadIdx.x; j < nvecs; j += stride) {
        float4 v = data[j];
        if (v.x != 0.0f || v.y != 0.0f || v.z != 0.0f || v.w != 0.0f) {
            int row = j / ROW_VECS;                 // compile-time const divisor -> magic mul
            int col = (j - row * ROW_VECS) * 4;
            if (v.x != 0.0f)      col += 0;
            else if (v.y != 0.0f) col += 1;
            else if (v.z != 0.0f) col += 2;
            else                  col += 3;
            out_idx[row] = col;                     // exactly one nonzero per row: no race
        }
    }
}

__device__ __forceinline__ float log_sigmoid(float x) {
    // stable: min(x,0) - log1p(exp(-|x|))
    return fminf(x, 0.0f) - log1pf(expf(-fabsf(x)));
}

// One wave (64 lanes) per batch element. EMB=300 -> 5 strided chunks per lane.
__global__ void cbow_loss_kernel(const int* __restrict__ idx_vo,
                                 const int* __restrict__ idx_vi,
                                 const int* __restrict__ idx_neg,
                                 const float* __restrict__ V,
                                 const float* __restrict__ U,
                                 float* __restrict__ out) {
    const int b = blockIdx.x;
    const int lane = threadIdx.x;   // blockDim.x == 64

    float vo_e[5] = {0.f, 0.f, 0.f, 0.f, 0.f};
    float vi_e[5] = {0.f, 0.f, 0.f, 0.f, 0.f};

    const int ivo = idx_vo[b];
    const float* __restrict__ vrow = V + (long)ivo * EMB;
#pragma unroll
    for (int j = 0; j < 5; ++j) {
        int d = lane + j * 64;
        if (d < EMB) vo_e[j] = vrow[d];
    }

    int cnt = 0;
#pragma unroll
    for (int c = 0; c < CTX; ++c) {
        int iv = idx_vi[b * CTX + c];
        if (iv >= 0) {
            ++cnt;
            const float* __restrict__ urow = U + (long)iv * EMB;
#pragma unroll
            for (int j = 0; j < 5; ++j) {
                int d = lane + j * 64;
                if (d < EMB) vi_e[j] += urow[d];
            }
        }
    }
    const float inv_cnt = 1.0f / (float)cnt;   // cnt >= 1 by construction (lengths >= 1)

    // left = log_sigmoid( dot(vo_embed, vi_embed) )
    float dot = 0.f;
#pragma unroll
    for (int j = 0; j < 5; ++j) dot += vo_e[j] * (vi_e[j] * inv_cnt);
#pragma unroll
    for (int off = 32; off > 0; off >>= 1) dot += __shfl_down(dot, off, 64);
    // lane 0 now holds the full dot

    float right = 0.f;
#pragma unroll
    for (int k = 0; k < KNEG; ++k) {
        int in = idx_neg[b * KNEG + k];
        const float* __restrict__ urow = U + (long)in * EMB;
        float pd = 0.f;
#pragma unroll
        for (int j = 0; j < 5; ++j) {
            int d = lane + j * 64;
            if (d < EMB) pd += vo_e[j] * urow[d];
        }
#pragma unroll
        for (int off = 32; off > 0; off >>= 1) pd += __shfl_down(pd, off, 64);
        if (lane == 0) right += log_sigmoid(-pd);
    }

    if (lane == 0) {
        float left = log_sigmoid(dot);
        atomicAdd(out, -(left + right) * (1.0f / (float)BSZ));
    }
}

extern "C" void kernel_launch(void* const* d_in, const int* in_sizes, int n_in,
                              void* d_out, int out_size, void* d_ws, size_t ws_size,
                              hipStream_t stream) {
    const float* vo  = (const float*)d_in[0];   // [B, VOC]
    const float* vi  = (const float*)d_in[1];   // [B, CTX, VOC]
    const float* neg = (const float*)d_in[2];   // [B, K, VOC]
    const float* V   = (const float*)d_in[3];   // [VOC, EMB]
    const float* U   = (const float*)d_in[4];   // [VOC, EMB]
    float* out = (float*)d_out;

    int* idx_vo  = (int*)d_ws;                  // B ints
    int* idx_vi  = idx_vo + BSZ;                // B*CTX ints
    int* idx_neg = idx_vi + BSZ * CTX;          // B*K ints
    const size_t idx_bytes = (size_t)(BSZ + BSZ * CTX + BSZ * KNEG) * sizeof(int);

    // ws is re-poisoned to 0xAA each launch: set indices to -1 (vi padding default)
    hipMemsetAsync(d_ws, 0xFF, idx_bytes, stream);
    hipMemsetAsync(d_out, 0, sizeof(float), stream);

    const int threads = 256;
    const int scan_blocks = 4096;

    scan_onehot_kernel<<<scan_blocks, threads, 0, stream>>>(
        (const float4*)vo, BSZ * ROW_VECS, idx_vo);
    scan_onehot_kernel<<<scan_blocks, threads, 0, stream>>>(
        (const float4*)vi, BSZ * CTX * ROW_VECS, idx_vi);
    scan_onehot_kernel<<<scan_blocks, threads, 0, stream>>>(
        (const float4*)neg, BSZ * KNEG * ROW_VECS, idx_neg);

    cbow_loss_kernel<<<BSZ, 64, 0, stream>>>(idx_vo, idx_vi, idx_neg, V, U, out);
}

// Round 3
// 885.607 us; speedup vs baseline: 1.0571x; 1.0571x over previous
//
#include <hip/hip_runtime.h>
#include <math.h>

#define VOC 50000
#define EMB 300
#define BSZ 256
#define CTX 6
#define KNEG 10
#define ROW_VECS (VOC / 4)            // 12500 float4 per one-hot row (VOC % 4 == 0)

#define NV_VO  (BSZ * ROW_VECS)           // 3.2M
#define NV_VI  (BSZ * CTX * ROW_VECS)     // 19.2M
#define NV_NEG (BSZ * KNEG * ROW_VECS)    // 32M

// native clang vector type: accepted by __builtin_nontemporal_load
typedef float floatx4 __attribute__((ext_vector_type(4)));

// Tiny init: idx arrays <- -1 (padded vi rows keep it), out <- 0.
__global__ void init_kernel(int* __restrict__ idx, int n, float* __restrict__ out) {
    int t = blockIdx.x * blockDim.x + threadIdx.x;
    for (int i = t; i < n; i += gridDim.x * blockDim.x) idx[i] = -1;
    if (t == 0) *out = 0.0f;
}

__device__ __forceinline__ void scan_segment(const floatx4* __restrict__ data,
                                             int nvecs,
                                             int* __restrict__ out_idx,
                                             int tid, int stride) {
    for (int j = tid; j < nvecs; j += stride) {
        floatx4 v = __builtin_nontemporal_load(&data[j]);
        if (v.x != 0.0f || v.y != 0.0f || v.z != 0.0f || v.w != 0.0f) {
            int row = j / ROW_VECS;              // const divisor -> magic mul
            int col = (j - row * ROW_VECS) * 4;
            if (v.x != 0.0f)      col += 0;
            else if (v.y != 0.0f) col += 1;
            else if (v.z != 0.0f) col += 2;
            else                  col += 3;
            out_idx[row] = col;                  // exactly one nonzero per row
        }
    }
}

// One fused streaming pass over vo (51 MB) + vi (307 MB) + neg (512 MB).
__global__ void scan_all_kernel(const floatx4* __restrict__ vo,
                                const floatx4* __restrict__ vi,
                                const floatx4* __restrict__ neg,
                                int* __restrict__ idx_vo,
                                int* __restrict__ idx_vi,
                                int* __restrict__ idx_neg) {
    const int tid = blockIdx.x * blockDim.x + threadIdx.x;
    const int stride = gridDim.x * blockDim.x;
    scan_segment(vo,  NV_VO,  idx_vo,  tid, stride);
    scan_segment(vi,  NV_VI,  idx_vi,  tid, stride);
    scan_segment(neg, NV_NEG, idx_neg, tid, stride);
}

__device__ __forceinline__ float log_sigmoid(float x) {
    return fminf(x, 0.0f) - log1pf(expf(-fabsf(x)));   // stable
}

// One wave (64 lanes) per batch element. EMB=300 -> 5 strided chunks per lane.
__global__ void cbow_loss_kernel(const int* __restrict__ idx_vo,
                                 const int* __restrict__ idx_vi,
                                 const int* __restrict__ idx_neg,
                                 const float* __restrict__ V,
                                 const float* __restrict__ U,
                                 float* __restrict__ out) {
    const int b = blockIdx.x;
    const int lane = threadIdx.x;   // blockDim.x == 64

    float vo_e[5] = {0.f, 0.f, 0.f, 0.f, 0.f};
    float vi_e[5] = {0.f, 0.f, 0.f, 0.f, 0.f};

    const int ivo = idx_vo[b];
    const float* __restrict__ vrow = V + (long)ivo * EMB;
#pragma unroll
    for (int j = 0; j < 5; ++j) {
        int d = lane + j * 64;
        if (d < EMB) vo_e[j] = vrow[d];
    }

    int cnt = 0;
#pragma unroll
    for (int c = 0; c < CTX; ++c) {
        int iv = idx_vi[b * CTX + c];
        if (iv >= 0) {
            ++cnt;
            const float* __restrict__ urow = U + (long)iv * EMB;
#pragma unroll
            for (int j = 0; j < 5; ++j) {
                int d = lane + j * 64;
                if (d < EMB) vi_e[j] += urow[d];
            }
        }
    }
    const float inv_cnt = 1.0f / (float)cnt;   // cnt >= 1 (lengths >= 1)

    float dot = 0.f;
#pragma unroll
    for (int j = 0; j < 5; ++j) dot += vo_e[j] * (vi_e[j] * inv_cnt);
#pragma unroll
    for (int off = 32; off > 0; off >>= 1) dot += __shfl_down(dot, off, 64);

    float right = 0.f;
#pragma unroll
    for (int k = 0; k < KNEG; ++k) {
        int in = idx_neg[b * KNEG + k];
        const float* __restrict__ urow = U + (long)in * EMB;
        float pd = 0.f;
#pragma unroll
        for (int j = 0; j < 5; ++j) {
            int d = lane + j * 64;
            if (d < EMB) pd += vo_e[j] * urow[d];
        }
#pragma unroll
        for (int off = 32; off > 0; off >>= 1) pd += __shfl_down(pd, off, 64);
        if (lane == 0) right += log_sigmoid(-pd);
    }

    if (lane == 0) {
        float left = log_sigmoid(dot);
        atomicAdd(out, -(left + right) * (1.0f / (float)BSZ));
    }
}

extern "C" void kernel_launch(void* const* d_in, const int* in_sizes, int n_in,
                              void* d_out, int out_size, void* d_ws, size_t ws_size,
                              hipStream_t stream) {
    const float* vo  = (const float*)d_in[0];   // [B, VOC]
    const float* vi  = (const float*)d_in[1];   // [B, CTX, VOC]
    const float* neg = (const float*)d_in[2];   // [B, K, VOC]
    const float* V   = (const float*)d_in[3];   // [VOC, EMB]
    const float* U   = (const float*)d_in[4];   // [VOC, EMB]
    float* out = (float*)d_out;

    int* idx_vo  = (int*)d_ws;                  // B
    int* idx_vi  = idx_vo + BSZ;                // B*CTX
    int* idx_neg = idx_vi + BSZ * CTX;          // B*K
    const int n_idx = BSZ + BSZ * CTX + BSZ * KNEG;   // 4352

    init_kernel<<<1, 256, 0, stream>>>(idx_vo, n_idx, out);

    // 4096 blocks x 256 = 16384 waves (64/CU), grid-stride streaming
    scan_all_kernel<<<4096, 256, 0, stream>>>(
        (const floatx4*)vo, (const floatx4*)vi, (const floatx4*)neg,
        idx_vo, idx_vi, idx_neg);

    cbow_loss_kernel<<<BSZ, 64, 0, stream>>>(idx_vo, idx_vi, idx_neg, V, U, out);
}

// Round 4
// 849.554 us; speedup vs baseline: 1.1019x; 1.0424x over previous
//
#include <hip/hip_runtime.h>
#include <math.h>

#define VOC 50000
#define EMB 300
#define BSZ 256
#define CTX 6
#define KNEG 10
#define ROW_VECS (VOC / 4)        // 12500 float4 per one-hot row (VOC % 4 == 0)
#define NROWS (BSZ + BSZ * CTX + BSZ * KNEG)   // 256 + 1536 + 2560 = 4352

// native clang vector type: accepted by __builtin_nontemporal_load
typedef float floatx4 __attribute__((ext_vector_type(4)));

// One 256-thread workgroup per one-hot row, early-exit once the nonzero is
// found. UNROLL=2: each thread tests 2 chunks (8 KB/block) per flag check.
// Double barrier makes the early-exit wave-uniform and race-free:
//   writes to `found` happen only before barrier1; reads only between
//   barrier1 and barrier2 -> all threads see the same value each round.
__global__ __launch_bounds__(256) void scan_rows_kernel(
        const floatx4* __restrict__ vo,
        const floatx4* __restrict__ vi,
        const floatx4* __restrict__ neg,
        int* __restrict__ out_idx,     // [NROWS]: vo rows, then vi, then neg
        float* __restrict__ out) {
    const int r = blockIdx.x;
    if (r == 0 && threadIdx.x == 0) *out = 0.0f;   // zero the loss accumulator

    const floatx4* __restrict__ row;
    if (r < BSZ)                 row = vo  + (size_t)r * ROW_VECS;
    else if (r < BSZ + BSZ*CTX)  row = vi  + (size_t)(r - BSZ) * ROW_VECS;
    else                         row = neg + (size_t)(r - BSZ - BSZ*CTX) * ROW_VECS;

    __shared__ int found;
    if (threadIdx.x == 0) found = 0;
    __syncthreads();

    const int t = threadIdx.x;   // 0..255
    for (int base = 0; base < ROW_VECS; base += 512) {
#pragma unroll
        for (int u = 0; u < 2; ++u) {
            int j = base + u * 256 + t;
            if (j < ROW_VECS) {
                floatx4 v = __builtin_nontemporal_load(&row[j]);
                if (v.x != 0.0f || v.y != 0.0f || v.z != 0.0f || v.w != 0.0f) {
                    int col = j * 4;
                    if (v.x != 0.0f)      col += 0;
                    else if (v.y != 0.0f) col += 1;
                    else if (v.z != 0.0f) col += 2;
                    else                  col += 3;
                    out_idx[r] = col;     // exactly one nonzero per row
                    found = 1;
                }
            }
        }
        __syncthreads();                  // barrier1: publish writes
        if (found) return;                // uniform: no writes since barrier1
        __syncthreads();                  // barrier2: all reads done before next round's writes
    }
    // all-zero (padded vi) row: record -1
    if (t == 0) out_idx[r] = -1;
}

__device__ __forceinline__ float log_sigmoid(float x) {
    return fminf(x, 0.0f) - log1pf(expf(-fabsf(x)));   // stable
}

// One wave (64 lanes) per batch element. EMB=300 -> 5 strided chunks per lane.
__global__ void cbow_loss_kernel(const int* __restrict__ idx_vo,
                                 const int* __restrict__ idx_vi,
                                 const int* __restrict__ idx_neg,
                                 const float* __restrict__ V,
                                 const float* __restrict__ U,
                                 float* __restrict__ out) {
    const int b = blockIdx.x;
    const int lane = threadIdx.x;   // blockDim.x == 64

    float vo_e[5] = {0.f, 0.f, 0.f, 0.f, 0.f};
    float vi_e[5] = {0.f, 0.f, 0.f, 0.f, 0.f};

    const int ivo = idx_vo[b];
    const float* __restrict__ vrow = V + (long)ivo * EMB;
#pragma unroll
    for (int j = 0; j < 5; ++j) {
        int d = lane + j * 64;
        if (d < EMB) vo_e[j] = vrow[d];
    }

    int cnt = 0;
#pragma unroll
    for (int c = 0; c < CTX; ++c) {
        int iv = idx_vi[b * CTX + c];
        if (iv >= 0) {
            ++cnt;
            const float* __restrict__ urow = U + (long)iv * EMB;
#pragma unroll
            for (int j = 0; j < 5; ++j) {
                int d = lane + j * 64;
                if (d < EMB) vi_e[j] += urow[d];
            }
        }
    }
    const float inv_cnt = 1.0f / (float)cnt;   // cnt >= 1 (lengths >= 1)

    float dot = 0.f;
#pragma unroll
    for (int j = 0; j < 5; ++j) dot += vo_e[j] * (vi_e[j] * inv_cnt);
#pragma unroll
    for (int off = 32; off > 0; off >>= 1) dot += __shfl_down(dot, off, 64);

    float right = 0.f;
#pragma unroll
    for (int k = 0; k < KNEG; ++k) {
        int in = idx_neg[b * KNEG + k];
        const float* __restrict__ urow = U + (long)in * EMB;
        float pd = 0.f;
#pragma unroll
        for (int j = 0; j < 5; ++j) {
            int d = lane + j * 64;
            if (d < EMB) pd += vo_e[j] * urow[d];
        }
#pragma unroll
        for (int off = 32; off > 0; off >>= 1) pd += __shfl_down(pd, off, 64);
        if (lane == 0) right += log_sigmoid(-pd);
    }

    if (lane == 0) {
        float left = log_sigmoid(dot);
        atomicAdd(out, -(left + right) * (1.0f / (float)BSZ));
    }
}

extern "C" void kernel_launch(void* const* d_in, const int* in_sizes, int n_in,
                              void* d_out, int out_size, void* d_ws, size_t ws_size,
                              hipStream_t stream) {
    const float* vo  = (const float*)d_in[0];   // [B, VOC]
    const float* vi  = (const float*)d_in[1];   // [B, CTX, VOC]
    const float* neg = (const float*)d_in[2];   // [B, K, VOC]
    const float* V   = (const float*)d_in[3];   // [VOC, EMB]
    const float* U   = (const float*)d_in[4];   // [VOC, EMB]
    float* out = (float*)d_out;

    int* idx_all = (int*)d_ws;                  // [NROWS]: vo | vi | neg
    int* idx_vo  = idx_all;
    int* idx_vi  = idx_all + BSZ;
    int* idx_neg = idx_all + BSZ + BSZ * CTX;

    scan_rows_kernel<<<NROWS, 256, 0, stream>>>(
        (const floatx4*)vo, (const floatx4*)vi, (const floatx4*)neg,
        idx_all, out);

    cbow_loss_kernel<<<BSZ, 64, 0, stream>>>(idx_vo, idx_vi, idx_neg, V, U, out);
}

// Round 5
// 837.179 us; speedup vs baseline: 1.1182x; 1.0148x over previous
//
#include <hip/hip_runtime.h>
#include <math.h>

#define VOC 50000
#define EMB 300
#define BSZ 256
#define CTX 6
#define KNEG 10
#define ROW_VECS (VOC / 4)        // 12500 float4 per one-hot row (VOC % 4 == 0)
#define NROWS (BSZ + BSZ * CTX + BSZ * KNEG)   // 4352

// native clang vector type: accepted by __builtin_nontemporal_load
typedef float floatx4 __attribute__((ext_vector_type(4)));

// One 256-thread workgroup per one-hot row, early-exit once the nonzero is
// found. UNROLL=4: each thread issues 4 independent 16B loads (16 KB/block)
// per flag check -> half the barrier rounds of UNROLL=2.
// Double barrier makes the early-exit race-free: writes to `found` happen
// only before barrier1; reads only between barrier1 and barrier2.
__global__ __launch_bounds__(256) void scan_rows_kernel(
        const floatx4* __restrict__ vo,
        const floatx4* __restrict__ vi,
        const floatx4* __restrict__ neg,
        int* __restrict__ out_idx,     // [NROWS]: vo rows, then vi, then neg
        float* __restrict__ out) {
    const int r = blockIdx.x;
    if (r == 0 && threadIdx.x == 0) *out = 0.0f;   // zero the loss accumulator

    const floatx4* __restrict__ row;
    if (r < BSZ)                 row = vo  + (size_t)r * ROW_VECS;
    else if (r < BSZ + BSZ*CTX)  row = vi  + (size_t)(r - BSZ) * ROW_VECS;
    else                         row = neg + (size_t)(r - BSZ - BSZ*CTX) * ROW_VECS;

    __shared__ int found;
    if (threadIdx.x == 0) found = 0;
    __syncthreads();

    const int t = threadIdx.x;   // 0..255
    for (int base = 0; base < ROW_VECS; base += 1024) {
        floatx4 v[4];
        int     j[4];
#pragma unroll
        for (int u = 0; u < 4; ++u) {
            j[u] = base + u * 256 + t;
            if (j[u] < ROW_VECS) v[u] = __builtin_nontemporal_load(&row[j[u]]);
            else                 v[u] = (floatx4)(0.f, 0.f, 0.f, 0.f);
        }
#pragma unroll
        for (int u = 0; u < 4; ++u) {
            if (v[u].x != 0.0f || v[u].y != 0.0f || v[u].z != 0.0f || v[u].w != 0.0f) {
                int col = j[u] * 4;
                if (v[u].x != 0.0f)      col += 0;
                else if (v[u].y != 0.0f) col += 1;
                else if (v[u].z != 0.0f) col += 2;
                else                     col += 3;
                out_idx[r] = col;         // exactly one nonzero per row
                found = 1;
            }
        }
        __syncthreads();                  // barrier1: publish writes
        if (found) return;                // uniform read
        __syncthreads();                  // barrier2: reads done before next round
    }
    if (t == 0) out_idx[r] = -1;          // all-zero (padded vi) row
}

__device__ __forceinline__ float log_sigmoid(float x) {
    return fminf(x, 0.0f) - log1pf(expf(-fabsf(x)));   // stable
}

// One wave (64 lanes) per batch element. EMB=300 -> 5 strided chunks per lane.
// All gathers restructured for memory-level parallelism: 6 vi rows branchless
// (weight 0 for padding), 10 neg rows into 10 independent accumulators.
__global__ void cbow_loss_kernel(const int* __restrict__ idx_vo,
                                 const int* __restrict__ idx_vi,
                                 const int* __restrict__ idx_neg,
                                 const float* __restrict__ V,
                                 const float* __restrict__ U,
                                 float* __restrict__ out) {
    const int b = blockIdx.x;
    const int lane = threadIdx.x;   // blockDim.x == 64

    // ---- load all indices first (independent scalar-ish loads) ----
    const int ivo = idx_vo[b];
    int ivi[CTX];
#pragma unroll
    for (int c = 0; c < CTX; ++c) ivi[c] = idx_vi[b * CTX + c];
    int ing[KNEG];
#pragma unroll
    for (int k = 0; k < KNEG; ++k) ing[k] = idx_neg[b * KNEG + k];

    int cnt = 0;
    float w[CTX];
    int   safe[CTX];
#pragma unroll
    for (int c = 0; c < CTX; ++c) {
        w[c] = (ivi[c] >= 0) ? 1.0f : 0.0f;
        safe[c] = (ivi[c] >= 0) ? ivi[c] : 0;
        cnt += (ivi[c] >= 0) ? 1 : 0;
    }
    const float inv_cnt = 1.0f / (float)cnt;   // cnt >= 1 (lengths >= 1)

    // ---- gather vo row ----
    float vo_e[5] = {0.f, 0.f, 0.f, 0.f, 0.f};
    const float* __restrict__ vrow = V + (long)ivo * EMB;
#pragma unroll
    for (int j = 0; j < 5; ++j) {
        int d = lane + j * 64;
        if (d < EMB) vo_e[j] = vrow[d];
    }

    // ---- gather all 6 context rows branchlessly (all loads in flight) ----
    float vi_e[5] = {0.f, 0.f, 0.f, 0.f, 0.f};
#pragma unroll
    for (int c = 0; c < CTX; ++c) {
        const float* __restrict__ urow = U + (long)safe[c] * EMB;
#pragma unroll
        for (int j = 0; j < 5; ++j) {
            int d = lane + j * 64;
            if (d < EMB) vi_e[j] += w[c] * urow[d];
        }
    }

    // ---- 10 negative dots, independent accumulators (50 loads in flight) ----
    float pd[KNEG];
#pragma unroll
    for (int k = 0; k < KNEG; ++k) pd[k] = 0.f;
#pragma unroll
    for (int k = 0; k < KNEG; ++k) {
        const float* __restrict__ urow = U + (long)ing[k] * EMB;
#pragma unroll
        for (int j = 0; j < 5; ++j) {
            int d = lane + j * 64;
            if (d < EMB) pd[k] += vo_e[j] * urow[d];
        }
    }

    // ---- reductions ----
    float dot = 0.f;
#pragma unroll
    for (int j = 0; j < 5; ++j) dot += vo_e[j] * (vi_e[j] * inv_cnt);
#pragma unroll
    for (int off = 32; off > 0; off >>= 1) dot += __shfl_down(dot, off, 64);

#pragma unroll
    for (int k = 0; k < KNEG; ++k) {
#pragma unroll
        for (int off = 32; off > 0; off >>= 1) pd[k] += __shfl_down(pd[k], off, 64);
    }

    if (lane == 0) {
        float right = 0.f;
#pragma unroll
        for (int k = 0; k < KNEG; ++k) right += log_sigmoid(-pd[k]);
        float left = log_sigmoid(dot);
        atomicAdd(out, -(left + right) * (1.0f / (float)BSZ));
    }
}

extern "C" void kernel_launch(void* const* d_in, const int* in_sizes, int n_in,
                              void* d_out, int out_size, void* d_ws, size_t ws_size,
                              hipStream_t stream) {
    const float* vo  = (const float*)d_in[0];   // [B, VOC]
    const float* vi  = (const float*)d_in[1];   // [B, CTX, VOC]
    const float* neg = (const float*)d_in[2];   // [B, K, VOC]
    const float* V   = (const float*)d_in[3];   // [VOC, EMB]
    const float* U   = (const float*)d_in[4];   // [VOC, EMB]
    float* out = (float*)d_out;

    int* idx_all = (int*)d_ws;                  // [NROWS]: vo | vi | neg
    int* idx_vo  = idx_all;
    int* idx_vi  = idx_all + BSZ;
    int* idx_neg = idx_all + BSZ + BSZ * CTX;

    scan_rows_kernel<<<NROWS, 256, 0, stream>>>(
        (const floatx4*)vo, (const floatx4*)vi, (const floatx4*)neg,
        idx_all, out);

    cbow_loss_kernel<<<BSZ, 64, 0, stream>>>(idx_vo, idx_vi, idx_neg, V, U, out);
}